// Round 14
// baseline (103.756 us; speedup 1.0000x reference)
//
#include <hip/hip_runtime.h>
#include <math.h>

// Problem constants (match reference)
#define N_ATOMS 256
#define N_FEAT  128
#define BATCH   8
#define BINS    300
#define INV_STEP 149.5f        // 1/STEP, STEP = 2/(BINS-1)
#define ONE_OVER_2PI 0.15915494309189535f
#define INV_112 0.8928571428571429f   // 1/1.12
#define WIN 2                  // bins beyond |d|=2 contribute < exp(-9)*|basis| ~ 1e-5 << tol
#define WINW 5                 // 2*WIN+1
#define NHIST 8                // privatized histogram copies per node

struct V3 { float x, y, z; };
__device__ __forceinline__ V3 v3sub(V3 a, V3 b) { return {a.x-b.x, a.y-b.y, a.z-b.z}; }
__device__ __forceinline__ float v3dot(V3 a, V3 b) { return a.x*b.x + a.y*b.y + a.z*b.z; }
__device__ __forceinline__ V3 v3cross(V3 a, V3 b) {
    return {a.y*b.z - a.z*b.y, a.z*b.x - a.x*b.z, a.x*b.y - a.y*b.x};
}
__device__ __forceinline__ V3 v3nrm(V3 a) {
    float r = __builtin_amdgcn_rsqf(v3dot(a, a));   // v_rsq_f32
    return {a.x*r, a.y*r, a.z*r};
}
__device__ __forceinline__ float clamp1(float x) { return fminf(1.0f, fmaxf(-1.0f, x)); }

// Branchless Cephes asinf: |x|<=0.5 poly; else pi/2 - 2*asin(sqrt((1-|x|)/2)).
__device__ __forceinline__ float asin_fast(float x) {
    float u = fabsf(x);
    bool big = u > 0.5f;
    float z = big ? 0.5f * (1.0f - u) : u * u;
    float s = big ? __builtin_amdgcn_sqrtf(z) : u;  // v_sqrt_f32
    float p = fmaf(z, 4.2163199048e-2f, 2.4181311049e-2f);
    p = fmaf(z, p, 4.5470025998e-2f);
    p = fmaf(z, p, 7.4953002686e-2f);
    p = fmaf(z, p, 1.6666752422e-1f);
    float r = fmaf(s * z, p, s);
    r = big ? (1.5707963267948966f - 2.0f * r) : r;
    return copysignf(r, x);
}

// writhe of segment pair (i,i+1),(j,j+1) from float4-padded LDS coords
// (each point = one ds_read_b128, consecutive lanes -> consecutive addresses)
__device__ __forceinline__ float writhe_ij(const float4* cs, int i, int j) {
    const float4 qi  = cs[i],   qi1 = cs[i + 1];
    const float4 qj  = cs[j],   qj1 = cs[j + 1];
    V3 pi  = {qi.x,  qi.y,  qi.z};
    V3 pi1 = {qi1.x, qi1.y, qi1.z};
    V3 pj  = {qj.x,  qj.y,  qj.z};
    V3 pj1 = {qj1.x, qj1.y, qj1.z};

    V3 d0 = v3nrm(v3sub(pj,  pi));
    V3 d1 = v3nrm(v3sub(pj1, pi));
    V3 d2 = v3nrm(v3sub(pj,  pi1));
    V3 d3 = v3nrm(v3sub(pj1, pi1));

    V3 c0 = v3nrm(v3cross(d0, d1));
    V3 c1 = v3nrm(v3cross(d1, d3));
    V3 c2 = v3nrm(v3cross(d3, d2));
    V3 c3 = v3nrm(v3cross(d2, d0));

    float omega = asin_fast(clamp1(v3dot(c0, c1)))
                + asin_fast(clamp1(v3dot(c1, c2)))
                + asin_fast(clamp1(v3dot(c2, c3)))
                + asin_fast(clamp1(v3dot(c3, c0)));

    float sg = v3dot(v3cross(v3sub(pj1, pj), v3sub(pi1, pi)), d0);
    float sign = (sg > 0.0f) ? 1.0f : ((sg < 0.0f) ? -1.0f : 0.0f);
    return omega * sign * ONE_OVER_2PI;
}

// One 512-thread block per NODE PAIR (t0, t1) = (p+2, 255-p), same batch.
// Edge counts sum to 508 for p>=1 (254 for p=0): one edge per thread.
// Node tau edges: type-1 = segment (a,tau), a in [0,tau-2] (iff tau<=254);
// type-2 = segment (a-1,tau-1), a in [1,tau-2]; weight g = exp(-|c_a-c_tau|^2).
// typ folded into ONE writhe call via shifted indices (a-typ, tau-typ):
// no divergent double execution of the ~250-instr writhe body.
__global__ __launch_bounds__(512) void fused_kernel(const float* __restrict__ coords,
                                                    const float* __restrict__ nf,
                                                    const float* __restrict__ basis,
                                                    float* __restrict__ out) {
    const int blk = blockIdx.x;
    const int b = blk & 7;
    const int p = blk >> 3;            // pair index 0..126
    const int t0 = p + 2;              // 2..128
    const int t1 = 255 - p;            // 255..129
    const int tid = threadIdx.x;

    const int E0  = 2 * t0 - 3;                         // edges of node t0 (>=1)
    const int E1n = (t1 == 255) ? 253 : 2 * t1 - 3;     // edges of node t1

    float mynf = 0.0f;
    if (tid < 256) {                   // prefetch nf rows t0 (tid<128) and t1
        const int row = (tid >> 7) ? t1 : t0;
        mynf = nf[((size_t)((b << 8) | row)) * N_FEAT + (tid & 127)];
    }

    __shared__ float4 cs[N_ATOMS];           // 4 KB, padded xyz0
    __shared__ float h2[2 * NHIST * BINS];   // 19.2 KB (two 8-copy histograms)
    __shared__ float part[4 * N_FEAT];       // 2 KB
    __shared__ float sden[2];
    __shared__ int skmin[2], skmax[2];

    if (tid < N_ATOMS) {
        const int gbase = ((b << 8) + tid) * 3;
        cs[tid] = make_float4(coords[gbase], coords[gbase + 1], coords[gbase + 2], 0.0f);
    }
    for (int k = tid; k < 2 * NHIST * BINS; k += 512) h2[k] = 0.0f;
    if (tid < 2) { sden[tid] = 0.0f; skmin[tid] = BINS - 1; skmax[tid] = 0; }
    __syncthreads();

    int node = -1;
    int tau = t0;
    if (tid < E0) { node = 0; tau = t0; }
    else if (tid < E0 + E1n) { node = 1; tau = t1; }
    const int ee = (node == 1) ? tid - E0 : tid;

    float d0 = 0.0f, d1 = 0.0f;
    int kn0 = BINS - 1, kx0 = 0, kn1 = BINS - 1, kx1 = 0;

    if (node >= 0) {
        const int eT1 = (tau <= N_ATOMS - 2) ? tau - 1 : 0;
        const int typ = (ee < eT1) ? 0 : 1;
        const int a = (typ == 0) ? ee : ee - eT1 + 1;

        const float4 qa = cs[a];
        const float4 qt = cs[tau];
        float dx = qa.x - qt.x;
        float dy = qa.y - qt.y;
        float dz = qa.z - qt.z;
        float g = __expf(-(dx*dx + dy*dy + dz*dz));

        // single call, shifted indices: segment (a-typ, tau-typ) covers both types
        float w = writhe_ij(cs, a - typ, tau - typ);
        float pp = (w + 1.0f) * INV_STEP;    // pp - k = (w - c_k)/STEP
        int k0 = __float2int_rn(pp);
        int kmn = max(0, k0 - WIN);
        int kmx = min(BINS - 1, k0 + WIN);
        if (node == 0) { d0 = g; kn0 = kmn; kx0 = kmx; }
        else           { d1 = g; kn1 = kmn; kx1 = kmx; }

        const int copy = tid & (NHIST - 1);
        const int rot = tid % WINW;          // (tid&7, tid%5): <=2-way alias in a wave (free)
        const int base = (node * NHIST + copy) * BINS;
        const int klo = k0 - WIN;
        #pragma unroll
        for (int m = 0; m < WINW; ++m) {
            int mm = m + rot; if (mm >= WINW) mm -= WINW;
            int k = klo + mm;
            if (k >= 0 && k < BINS) {
                float dd = pp - (float)k;
                atomicAdd(&h2[base + k], g * __expf(-dd * dd));
            }
        }
    }

    // per-wave masked butterflies for both nodes, one LDS atomic set per wave
    #pragma unroll
    for (int off = 32; off > 0; off >>= 1) {
        d0 += __shfl_xor(d0, off, 64);
        d1 += __shfl_xor(d1, off, 64);
        kn0 = min(kn0, __shfl_xor(kn0, off, 64));
        kx0 = max(kx0, __shfl_xor(kx0, off, 64));
        kn1 = min(kn1, __shfl_xor(kn1, off, 64));
        kx1 = max(kx1, __shfl_xor(kx1, off, 64));
    }
    if ((tid & 63) == 0) {
        atomicAdd(&sden[0], d0);
        atomicAdd(&sden[1], d1);
        atomicMin(&skmin[0], kn0);
        atomicMax(&skmax[0], kx0);
        atomicMin(&skmin[1], kn1);
        atomicMax(&skmax[1], kx1);
    }
    __syncthreads();

    // combine the 8 privatized copies per node, over touched range only
    {
        const int nu = tid >> 8;             // 256 threads per node
        const int kmin = skmin[nu], kmax = skmax[nu];
        const int base = nu * NHIST * BINS;
        for (int k = kmin + (tid & 255); k <= kmax; k += 256) {
            float s = h2[base + k];
            #pragma unroll
            for (int c = 1; c < NHIST; ++c) s += h2[base + c * BINS + k];
            h2[base + k] = s;
        }
    }
    __syncthreads();

    // projection: 2 nodes x 2 bin-halves x 128 features
    {
        const int nu = tid >> 8;
        const int h = (tid >> 7) & 1;
        const int f = tid & 127;
        const int kmin = skmin[nu], kmax = skmax[nu];
        const int len = kmax - kmin + 1;
        const int half = (len + 1) >> 1;
        const int ks = kmin + h * half;
        const int ke = min(kmax + 1, ks + half);
        const int base = nu * NHIST * BINS;
        float acc = 0.0f;
        for (int k = ks; k < ke; ++k)
            acc = fmaf(h2[base + k], basis[k * N_FEAT + f], acc);
        part[((nu << 1) | h) * N_FEAT + f] = acc;
    }
    __syncthreads();

    if (tid < 256) {
        const int nu = tid >> 7;
        const int f = tid & 127;
        const int row = nu ? t1 : t0;
        const float scale = INV_112 / sden[nu];
        const float s = part[(nu << 1) * N_FEAT + f] + part[((nu << 1) | 1) * N_FEAT + f];
        out[((size_t)((b << 8) | row)) * N_FEAT + f] = mynf + s * scale;
    } else if (p == 0) {
        // passthrough rows t = 0, 1 (no incoming edges), handled by the (2,255) block
        const int tid2 = tid - 256;
        const int r = tid2 >> 7;
        const int f = tid2 & 127;
        const size_t idx = ((size_t)((b << 8) | r)) * N_FEAT + f;
        out[idx] = nf[idx];
    }
}

extern "C" void kernel_launch(void* const* d_in, const int* in_sizes, int n_in,
                              void* d_out, int out_size, void* d_ws, size_t ws_size,
                              hipStream_t stream) {
    const float* coords = (const float*)d_in[0];   // (B*N, 3) f32
    const float* nf     = (const float*)d_in[1];   // (B*N, 128) f32
    const float* basis  = (const float*)d_in[2];   // (300, 128) f32
    float* out = (float*)d_out;                    // (B*N, 128) f32

    fused_kernel<<<BATCH * 127, 512, 0, stream>>>(coords, nf, basis, out);
}

// Round 15
// 103.337 us; speedup vs baseline: 1.0041x; 1.0041x over previous
//
#include <hip/hip_runtime.h>
#include <math.h>

// Problem constants (match reference)
#define N_ATOMS 256
#define N_FEAT  128
#define BATCH   8
#define BINS    300
#define INV_STEP 149.5f        // 1/STEP, STEP = 2/(BINS-1)
#define ONE_OVER_2PI 0.15915494309189535f
#define INV_112 0.8928571428571429f   // 1/1.12
#define WIN 2                  // bins beyond |d|=2 contribute < exp(-9)*|basis| ~ 1e-5 << tol
#define WINW 5                 // 2*WIN+1
#define NHIST 8                // privatized histogram copies per node
#define EXPM2 0.13533528323661270f    // e^-2

struct V3 { float x, y, z; };
__device__ __forceinline__ V3 v3sub(V3 a, V3 b) { return {a.x-b.x, a.y-b.y, a.z-b.z}; }
__device__ __forceinline__ float v3dot(V3 a, V3 b) { return a.x*b.x + a.y*b.y + a.z*b.z; }
__device__ __forceinline__ V3 v3cross(V3 a, V3 b) {
    return {a.y*b.z - a.z*b.y, a.z*b.x - a.x*b.z, a.x*b.y - a.y*b.x};
}
__device__ __forceinline__ V3 v3nrm(V3 a) {
    float r = __builtin_amdgcn_rsqf(v3dot(a, a));   // v_rsq_f32
    return {a.x*r, a.y*r, a.z*r};
}
__device__ __forceinline__ float clamp1(float x) { return fminf(1.0f, fmaxf(-1.0f, x)); }

// Branchless Cephes asinf: |x|<=0.5 poly; else pi/2 - 2*asin(sqrt((1-|x|)/2)).
__device__ __forceinline__ float asin_fast(float x) {
    float u = fabsf(x);
    bool big = u > 0.5f;
    float z = big ? 0.5f * (1.0f - u) : u * u;
    float s = big ? __builtin_amdgcn_sqrtf(z) : u;  // v_sqrt_f32
    float p = fmaf(z, 4.2163199048e-2f, 2.4181311049e-2f);
    p = fmaf(z, p, 4.5470025998e-2f);
    p = fmaf(z, p, 7.4953002686e-2f);
    p = fmaf(z, p, 1.6666752422e-1f);
    float r = fmaf(s * z, p, s);
    r = big ? (1.5707963267948966f - 2.0f * r) : r;
    return copysignf(r, x);
}

// writhe of segment pair (i,i+1),(j,j+1) from float4-padded LDS coords
__device__ __forceinline__ float writhe_ij(const float4* cs, int i, int j) {
    const float4 qi  = cs[i],   qi1 = cs[i + 1];
    const float4 qj  = cs[j],   qj1 = cs[j + 1];
    V3 pi  = {qi.x,  qi.y,  qi.z};
    V3 pi1 = {qi1.x, qi1.y, qi1.z};
    V3 pj  = {qj.x,  qj.y,  qj.z};
    V3 pj1 = {qj1.x, qj1.y, qj1.z};

    V3 d0 = v3nrm(v3sub(pj,  pi));
    V3 d1 = v3nrm(v3sub(pj1, pi));
    V3 d2 = v3nrm(v3sub(pj,  pi1));
    V3 d3 = v3nrm(v3sub(pj1, pi1));

    V3 c0 = v3nrm(v3cross(d0, d1));
    V3 c1 = v3nrm(v3cross(d1, d3));
    V3 c2 = v3nrm(v3cross(d3, d2));
    V3 c3 = v3nrm(v3cross(d2, d0));

    float omega = asin_fast(clamp1(v3dot(c0, c1)))
                + asin_fast(clamp1(v3dot(c1, c2)))
                + asin_fast(clamp1(v3dot(c2, c3)))
                + asin_fast(clamp1(v3dot(c3, c0)));

    float sg = v3dot(v3cross(v3sub(pj1, pj), v3sub(pi1, pi)), d0);
    float sign = (sg > 0.0f) ? 1.0f : ((sg < 0.0f) ? -1.0f : 0.0f);
    return omega * sign * ONE_OVER_2PI;
}

// One 512-thread block per NODE PAIR (t0, t1) = (p+2, 255-p), same batch.
// Edge counts sum to 508 for p>=1 (254 for p=0): one edge per thread.
// Phases: compute (writhe,g,k0 in regs) -> range-reduce -> lazy-zero only the
// touched bin range of all 16 histogram copies -> deposit (exp-recurrence,
// g-folded, no rotation) -> combine -> project.
__global__ __launch_bounds__(512) void fused_kernel(const float* __restrict__ coords,
                                                    const float* __restrict__ nf,
                                                    const float* __restrict__ basis,
                                                    float* __restrict__ out) {
    const int blk = blockIdx.x;
    const int b = blk & 7;
    const int p = blk >> 3;            // pair index 0..126
    const int t0 = p + 2;              // 2..128
    const int t1 = 255 - p;            // 255..129
    const int tid = threadIdx.x;

    const int E0  = 2 * t0 - 3;                         // edges of node t0 (>=1)
    const int E1n = (t1 == 255) ? 253 : 2 * t1 - 3;     // edges of node t1

    float mynf = 0.0f;
    if (tid < 256) {                   // prefetch nf rows t0 (tid<128) and t1
        const int row = (tid >> 7) ? t1 : t0;
        mynf = nf[((size_t)((b << 8) | row)) * N_FEAT + (tid & 127)];
    }

    __shared__ float4 cs[N_ATOMS];           // 4 KB, padded xyz0
    __shared__ float h2[2 * NHIST * BINS];   // 19.2 KB (two 8-copy histograms)
    __shared__ float part[4 * N_FEAT];       // 2 KB
    __shared__ float sden[2];
    __shared__ int skmin[2], skmax[2];

    if (tid < N_ATOMS) {
        const int gbase = ((b << 8) + tid) * 3;
        cs[tid] = make_float4(coords[gbase], coords[gbase + 1], coords[gbase + 2], 0.0f);
    }
    if (tid < 2) { sden[tid] = 0.0f; skmin[tid] = BINS - 1; skmax[tid] = 0; }
    __syncthreads();

    int node = -1;
    int tau = t0;
    if (tid < E0) { node = 0; tau = t0; }
    else if (tid < E0 + E1n) { node = 1; tau = t1; }
    const int ee = (node == 1) ? tid - E0 : tid;

    float g = 0.0f, pp = 0.0f;
    int k0 = 0;
    float d0 = 0.0f, d1 = 0.0f;
    int kn0 = BINS - 1, kx0 = 0, kn1 = BINS - 1, kx1 = 0;

    if (node >= 0) {
        const int eT1 = (tau <= N_ATOMS - 2) ? tau - 1 : 0;
        const int typ = (ee < eT1) ? 0 : 1;
        const int a = (typ == 0) ? ee : ee - eT1 + 1;

        const float4 qa = cs[a];
        const float4 qt = cs[tau];
        float dx = qa.x - qt.x;
        float dy = qa.y - qt.y;
        float dz = qa.z - qt.z;
        g = __expf(-(dx*dx + dy*dy + dz*dz));

        // single call, shifted indices: segment (a-typ, tau-typ) covers both types
        float w = writhe_ij(cs, a - typ, tau - typ);
        pp = (w + 1.0f) * INV_STEP;          // pp - k = (w - c_k)/STEP
        k0 = __float2int_rn(pp);
        int kmn = max(0, k0 - WIN);
        int kmx = min(BINS - 1, k0 + WIN);
        if (node == 0) { d0 = g; kn0 = kmn; kx0 = kmx; }
        else           { d1 = g; kn1 = kmn; kx1 = kmx; }
    }

    // per-wave masked butterflies for both nodes, one LDS atomic set per wave
    #pragma unroll
    for (int off = 32; off > 0; off >>= 1) {
        d0 += __shfl_xor(d0, off, 64);
        d1 += __shfl_xor(d1, off, 64);
        kn0 = min(kn0, __shfl_xor(kn0, off, 64));
        kx0 = max(kx0, __shfl_xor(kx0, off, 64));
        kn1 = min(kn1, __shfl_xor(kn1, off, 64));
        kx1 = max(kx1, __shfl_xor(kx1, off, 64));
    }
    if ((tid & 63) == 0) {
        atomicAdd(&sden[0], d0);
        atomicAdd(&sden[1], d1);
        atomicMin(&skmin[0], kn0);
        atomicMax(&skmax[0], kx0);
        atomicMin(&skmin[1], kn1);
        atomicMax(&skmax[1], kx1);
    }
    __syncthreads();

    // lazy zero: only the touched range of all NHIST copies, both nodes
    {
        const int nu = tid >> 8;             // 256 threads per node
        const int l = tid & 255;
        const int kmin = skmin[nu], kmax = skmax[nu];
        const int base = nu * NHIST * BINS;
        for (int k = kmin + l; k <= kmax; k += 256) {
            #pragma unroll
            for (int c = 0; c < NHIST; ++c) h2[base + c * BINS + k] = 0.0f;
        }
    }
    __syncthreads();

    // deposit: exp-recurrence over the 5-bin window, g folded into the seed
    if (node >= 0) {
        const int base = (node * NHIST + (tid & (NHIST - 1))) * BINS;
        const int klo = k0 - WIN;
        float d = pp - (float)klo;
        float e = g * __expf(-d * d);        // g * w(klo)
        float u = __expf(2.0f * d - 1.0f);   // ratio w(k+1)/w(k) at klo
        #pragma unroll
        for (int m = 0; m < WINW; ++m) {
            const int k = klo + m;
            if (k >= 0 && k < BINS) atomicAdd(&h2[base + k], e);
            e *= u;
            u *= EXPM2;
        }
    }
    __syncthreads();

    // combine the 8 privatized copies per node, over touched range only
    {
        const int nu = tid >> 8;
        const int kmin = skmin[nu], kmax = skmax[nu];
        const int base = nu * NHIST * BINS;
        for (int k = kmin + (tid & 255); k <= kmax; k += 256) {
            float s = h2[base + k];
            #pragma unroll
            for (int c = 1; c < NHIST; ++c) s += h2[base + c * BINS + k];
            h2[base + k] = s;
        }
    }
    __syncthreads();

    // projection: 2 nodes x 2 bin-halves x 128 features
    {
        const int nu = tid >> 8;
        const int h = (tid >> 7) & 1;
        const int f = tid & 127;
        const int kmin = skmin[nu], kmax = skmax[nu];
        const int len = kmax - kmin + 1;
        const int half = (len + 1) >> 1;
        const int ks = kmin + h * half;
        const int ke = min(kmax + 1, ks + half);
        const int base = nu * NHIST * BINS;
        float acc = 0.0f;
        for (int k = ks; k < ke; ++k)
            acc = fmaf(h2[base + k], basis[k * N_FEAT + f], acc);
        part[((nu << 1) | h) * N_FEAT + f] = acc;
    }
    __syncthreads();

    if (tid < 256) {
        const int nu = tid >> 7;
        const int f = tid & 127;
        const int row = nu ? t1 : t0;
        const float scale = INV_112 / sden[nu];
        const float s = part[(nu << 1) * N_FEAT + f] + part[((nu << 1) | 1) * N_FEAT + f];
        out[((size_t)((b << 8) | row)) * N_FEAT + f] = mynf + s * scale;
    } else if (p == 0) {
        // passthrough rows t = 0, 1 (no incoming edges), handled by the (2,255) block
        const int tid2 = tid - 256;
        const int r = tid2 >> 7;
        const int f = tid2 & 127;
        const size_t idx = ((size_t)((b << 8) | r)) * N_FEAT + f;
        out[idx] = nf[idx];
    }
}

extern "C" void kernel_launch(void* const* d_in, const int* in_sizes, int n_in,
                              void* d_out, int out_size, void* d_ws, size_t ws_size,
                              hipStream_t stream) {
    const float* coords = (const float*)d_in[0];   // (B*N, 3) f32
    const float* nf     = (const float*)d_in[1];   // (B*N, 128) f32
    const float* basis  = (const float*)d_in[2];   // (300, 128) f32
    float* out = (float*)d_out;                    // (B*N, 128) f32

    fused_kernel<<<BATCH * 127, 512, 0, stream>>>(coords, nf, basis, out);
}

// Round 16
// 103.210 us; speedup vs baseline: 1.0053x; 1.0012x over previous
//
#include <hip/hip_runtime.h>
#include <math.h>

// Problem constants (match reference)
#define N_ATOMS 256
#define N_FEAT  128
#define BATCH   8
#define BINS    300
#define INV_STEP 149.5f        // 1/STEP, STEP = 2/(BINS-1)
#define ONE_OVER_2PI 0.15915494309189535f
#define INV_112 0.8928571428571429f   // 1/1.12
#define WIN 2                  // bins beyond |d|=2 contribute < exp(-9)*|basis| ~ 1e-5 << tol
#define WINW 5                 // 2*WIN+1
#define NHIST 8                // privatized histogram copies per node
#define EXPM2 0.13533528323661270f    // e^-2

struct V3 { float x, y, z; };
__device__ __forceinline__ V3 v3sub(V3 a, V3 b) { return {a.x-b.x, a.y-b.y, a.z-b.z}; }
__device__ __forceinline__ float v3dot(V3 a, V3 b) { return a.x*b.x + a.y*b.y + a.z*b.z; }
__device__ __forceinline__ V3 v3cross(V3 a, V3 b) {
    return {a.y*b.z - a.z*b.y, a.z*b.x - a.x*b.z, a.x*b.y - a.y*b.x};
}
__device__ __forceinline__ float clamp1(float x) { return fminf(1.0f, fmaxf(-1.0f, x)); }

// Branchless Cephes asinf: |x|<=0.5 poly; else pi/2 - 2*asin(sqrt((1-|x|)/2)).
__device__ __forceinline__ float asin_fast(float x) {
    float u = fabsf(x);
    bool big = u > 0.5f;
    float z = big ? 0.5f * (1.0f - u) : u * u;
    float s = big ? __builtin_amdgcn_sqrtf(z) : u;  // v_sqrt_f32
    float p = fmaf(z, 4.2163199048e-2f, 2.4181311049e-2f);
    p = fmaf(z, p, 4.5470025998e-2f);
    p = fmaf(z, p, 7.4953002686e-2f);
    p = fmaf(z, p, 1.6666752422e-1f);
    float r = fmaf(s * z, p, s);
    r = big ? (1.5707963267948966f - 2.0f * r) : r;
    return copysignf(r, x);
}

// writhe of segment pair (i,i+1),(j,j+1) from float4-padded LDS coords.
// Algebraic reduction vs reference: direction normalization is redundant —
// cross(u0,u1) = |u0||u1| * cross(d0,d1) with positive scale, so normalizing
// the raw crosses gives identical unit vectors; the sign dot only needs an
// unnormalized u0. 4 rsq instead of 8, same values up to FP rounding.
__device__ __forceinline__ float writhe_ij(const float4* cs, int i, int j) {
    const float4 qi  = cs[i],   qi1 = cs[i + 1];
    const float4 qj  = cs[j],   qj1 = cs[j + 1];
    V3 pi  = {qi.x,  qi.y,  qi.z};
    V3 pi1 = {qi1.x, qi1.y, qi1.z};
    V3 pj  = {qj.x,  qj.y,  qj.z};
    V3 pj1 = {qj1.x, qj1.y, qj1.z};

    V3 u0 = v3sub(pj,  pi);     // unnormalized directions
    V3 u1 = v3sub(pj1, pi);
    V3 u2 = v3sub(pj,  pi1);
    V3 u3 = v3sub(pj1, pi1);

    V3 c0 = v3cross(u0, u1);    // raw crosses (positive multiples of ref's)
    V3 c1 = v3cross(u1, u3);
    V3 c2 = v3cross(u3, u2);
    V3 c3 = v3cross(u2, u0);

    float r0 = __builtin_amdgcn_rsqf(v3dot(c0, c0));
    float r1 = __builtin_amdgcn_rsqf(v3dot(c1, c1));
    float r2 = __builtin_amdgcn_rsqf(v3dot(c2, c2));
    float r3 = __builtin_amdgcn_rsqf(v3dot(c3, c3));

    float omega = asin_fast(clamp1(v3dot(c0, c1) * (r0 * r1)))
                + asin_fast(clamp1(v3dot(c1, c2) * (r1 * r2)))
                + asin_fast(clamp1(v3dot(c2, c3) * (r2 * r3)))
                + asin_fast(clamp1(v3dot(c3, c0) * (r3 * r0)));

    float sg = v3dot(v3cross(v3sub(pj1, pj), v3sub(pi1, pi)), u0);
    float sign = (sg > 0.0f) ? 1.0f : ((sg < 0.0f) ? -1.0f : 0.0f);
    return omega * sign * ONE_OVER_2PI;
}

// One 512-thread block per NODE PAIR (t0, t1) = (p+2, 255-p), same batch.
// Edge counts sum to 508 for p>=1 (254 for p=0): one edge per thread.
// Phases: compute (writhe,g,k0 in regs) -> range-reduce -> lazy-zero only the
// touched bin range of all 16 histogram copies -> deposit (exp-recurrence,
// g-folded) -> combine -> project.
__global__ __launch_bounds__(512) void fused_kernel(const float* __restrict__ coords,
                                                    const float* __restrict__ nf,
                                                    const float* __restrict__ basis,
                                                    float* __restrict__ out) {
    const int blk = blockIdx.x;
    const int b = blk & 7;
    const int p = blk >> 3;            // pair index 0..126
    const int t0 = p + 2;              // 2..128
    const int t1 = 255 - p;            // 255..129
    const int tid = threadIdx.x;

    const int E0  = 2 * t0 - 3;                         // edges of node t0 (>=1)
    const int E1n = (t1 == 255) ? 253 : 2 * t1 - 3;     // edges of node t1

    float mynf = 0.0f;
    if (tid < 256) {                   // prefetch nf rows t0 (tid<128) and t1
        const int row = (tid >> 7) ? t1 : t0;
        mynf = nf[((size_t)((b << 8) | row)) * N_FEAT + (tid & 127)];
    }

    __shared__ float4 cs[N_ATOMS];           // 4 KB, padded xyz0
    __shared__ float h2[2 * NHIST * BINS];   // 19.2 KB (two 8-copy histograms)
    __shared__ float part[4 * N_FEAT];       // 2 KB
    __shared__ float sden[2];
    __shared__ int skmin[2], skmax[2];

    if (tid < N_ATOMS) {
        const int gbase = ((b << 8) + tid) * 3;
        cs[tid] = make_float4(coords[gbase], coords[gbase + 1], coords[gbase + 2], 0.0f);
    }
    if (tid < 2) { sden[tid] = 0.0f; skmin[tid] = BINS - 1; skmax[tid] = 0; }
    __syncthreads();

    int node = -1;
    int tau = t0;
    if (tid < E0) { node = 0; tau = t0; }
    else if (tid < E0 + E1n) { node = 1; tau = t1; }
    const int ee = (node == 1) ? tid - E0 : tid;

    float g = 0.0f, pp = 0.0f;
    int k0 = 0;
    float d0 = 0.0f, d1 = 0.0f;
    int kn0 = BINS - 1, kx0 = 0, kn1 = BINS - 1, kx1 = 0;

    if (node >= 0) {
        const int eT1 = (tau <= N_ATOMS - 2) ? tau - 1 : 0;
        const int typ = (ee < eT1) ? 0 : 1;
        const int a = (typ == 0) ? ee : ee - eT1 + 1;

        const float4 qa = cs[a];
        const float4 qt = cs[tau];
        float dx = qa.x - qt.x;
        float dy = qa.y - qt.y;
        float dz = qa.z - qt.z;
        g = __expf(-(dx*dx + dy*dy + dz*dz));

        // single call, shifted indices: segment (a-typ, tau-typ) covers both types
        float w = writhe_ij(cs, a - typ, tau - typ);
        pp = (w + 1.0f) * INV_STEP;          // pp - k = (w - c_k)/STEP
        k0 = __float2int_rn(pp);
        int kmn = max(0, k0 - WIN);
        int kmx = min(BINS - 1, k0 + WIN);
        if (node == 0) { d0 = g; kn0 = kmn; kx0 = kmx; }
        else           { d1 = g; kn1 = kmn; kx1 = kmx; }
    }

    // per-wave masked butterflies for both nodes, one LDS atomic set per wave
    #pragma unroll
    for (int off = 32; off > 0; off >>= 1) {
        d0 += __shfl_xor(d0, off, 64);
        d1 += __shfl_xor(d1, off, 64);
        kn0 = min(kn0, __shfl_xor(kn0, off, 64));
        kx0 = max(kx0, __shfl_xor(kx0, off, 64));
        kn1 = min(kn1, __shfl_xor(kn1, off, 64));
        kx1 = max(kx1, __shfl_xor(kx1, off, 64));
    }
    if ((tid & 63) == 0) {
        atomicAdd(&sden[0], d0);
        atomicAdd(&sden[1], d1);
        atomicMin(&skmin[0], kn0);
        atomicMax(&skmax[0], kx0);
        atomicMin(&skmin[1], kn1);
        atomicMax(&skmax[1], kx1);
    }
    __syncthreads();

    // lazy zero: only the touched range of all NHIST copies, both nodes
    {
        const int nu = tid >> 8;             // 256 threads per node
        const int l = tid & 255;
        const int kmin = skmin[nu], kmax = skmax[nu];
        const int base = nu * NHIST * BINS;
        for (int k = kmin + l; k <= kmax; k += 256) {
            #pragma unroll
            for (int c = 0; c < NHIST; ++c) h2[base + c * BINS + k] = 0.0f;
        }
    }
    __syncthreads();

    // deposit: exp-recurrence over the 5-bin window, g folded into the seed
    if (node >= 0) {
        const int base = (node * NHIST + (tid & (NHIST - 1))) * BINS;
        const int klo = k0 - WIN;
        float d = pp - (float)klo;
        float e = g * __expf(-d * d);        // g * w(klo)
        float u = __expf(2.0f * d - 1.0f);   // ratio w(k+1)/w(k) at klo
        #pragma unroll
        for (int m = 0; m < WINW; ++m) {
            const int k = klo + m;
            if (k >= 0 && k < BINS) atomicAdd(&h2[base + k], e);
            e *= u;
            u *= EXPM2;
        }
    }
    __syncthreads();

    // combine the 8 privatized copies per node, over touched range only
    {
        const int nu = tid >> 8;
        const int kmin = skmin[nu], kmax = skmax[nu];
        const int base = nu * NHIST * BINS;
        for (int k = kmin + (tid & 255); k <= kmax; k += 256) {
            float s = h2[base + k];
            #pragma unroll
            for (int c = 1; c < NHIST; ++c) s += h2[base + c * BINS + k];
            h2[base + k] = s;
        }
    }
    __syncthreads();

    // projection: 2 nodes x 2 bin-halves x 128 features
    {
        const int nu = tid >> 8;
        const int h = (tid >> 7) & 1;
        const int f = tid & 127;
        const int kmin = skmin[nu], kmax = skmax[nu];
        const int len = kmax - kmin + 1;
        const int half = (len + 1) >> 1;
        const int ks = kmin + h * half;
        const int ke = min(kmax + 1, ks + half);
        const int base = nu * NHIST * BINS;
        float acc = 0.0f;
        for (int k = ks; k < ke; ++k)
            acc = fmaf(h2[base + k], basis[k * N_FEAT + f], acc);
        part[((nu << 1) | h) * N_FEAT + f] = acc;
    }
    __syncthreads();

    if (tid < 256) {
        const int nu = tid >> 7;
        const int f = tid & 127;
        const int row = nu ? t1 : t0;
        const float scale = INV_112 / sden[nu];
        const float s = part[(nu << 1) * N_FEAT + f] + part[((nu << 1) | 1) * N_FEAT + f];
        out[((size_t)((b << 8) | row)) * N_FEAT + f] = mynf + s * scale;
    } else if (p == 0) {
        // passthrough rows t = 0, 1 (no incoming edges), handled by the (2,255) block
        const int tid2 = tid - 256;
        const int r = tid2 >> 7;
        const int f = tid2 & 127;
        const size_t idx = ((size_t)((b << 8) | r)) * N_FEAT + f;
        out[idx] = nf[idx];
    }
}

extern "C" void kernel_launch(void* const* d_in, const int* in_sizes, int n_in,
                              void* d_out, int out_size, void* d_ws, size_t ws_size,
                              hipStream_t stream) {
    const float* coords = (const float*)d_in[0];   // (B*N, 3) f32
    const float* nf     = (const float*)d_in[1];   // (B*N, 128) f32
    const float* basis  = (const float*)d_in[2];   // (300, 128) f32
    float* out = (float*)d_out;                    // (B*N, 128) f32

    fused_kernel<<<BATCH * 127, 512, 0, stream>>>(coords, nf, basis, out);
}

// Round 17
// 99.334 us; speedup vs baseline: 1.0445x; 1.0390x over previous
//
#include <hip/hip_runtime.h>
#include <math.h>

// Problem constants (match reference)
#define N_ATOMS 256
#define N_FEAT  128
#define BATCH   8
#define BINS    300
#define INV_STEP 149.5f        // 1/STEP, STEP = 2/(BINS-1)
#define ONE_OVER_2PI 0.15915494309189535f
#define INV_112 0.8928571428571429f   // 1/1.12
#define WIN 2                  // bins beyond |d|=2 contribute < exp(-9)*|basis| ~ 1e-5 << tol
#define WINW 5                 // 2*WIN+1
#define NHIST 4                // privatized histogram copies per node
#define EXPM2 0.13533528323661270f    // e^-2

struct V3 { float x, y, z; };
__device__ __forceinline__ V3 v3sub(V3 a, V3 b) { return {a.x-b.x, a.y-b.y, a.z-b.z}; }
__device__ __forceinline__ float v3dot(V3 a, V3 b) { return a.x*b.x + a.y*b.y + a.z*b.z; }
__device__ __forceinline__ V3 v3cross(V3 a, V3 b) {
    return {a.y*b.z - a.z*b.y, a.z*b.x - a.x*b.z, a.x*b.y - a.y*b.x};
}
__device__ __forceinline__ float clamp1(float x) { return fminf(1.0f, fmaxf(-1.0f, x)); }

// Branchless Cephes asinf: |x|<=0.5 poly; else pi/2 - 2*asin(sqrt((1-|x|)/2)).
__device__ __forceinline__ float asin_fast(float x) {
    float u = fabsf(x);
    bool big = u > 0.5f;
    float z = big ? 0.5f * (1.0f - u) : u * u;
    float s = big ? __builtin_amdgcn_sqrtf(z) : u;  // v_sqrt_f32
    float p = fmaf(z, 4.2163199048e-2f, 2.4181311049e-2f);
    p = fmaf(z, p, 4.5470025998e-2f);
    p = fmaf(z, p, 7.4953002686e-2f);
    p = fmaf(z, p, 1.6666752422e-1f);
    float r = fmaf(s * z, p, s);
    r = big ? (1.5707963267948966f - 2.0f * r) : r;
    return copysignf(r, x);
}

// writhe of segment pair (i,i+1),(j,j+1) from float4-padded LDS coords.
// Direction normalization algebraically removed (4 rsq instead of 8).
__device__ __forceinline__ float writhe_ij(const float4* cs, int i, int j) {
    const float4 qi  = cs[i],   qi1 = cs[i + 1];
    const float4 qj  = cs[j],   qj1 = cs[j + 1];
    V3 pi  = {qi.x,  qi.y,  qi.z};
    V3 pi1 = {qi1.x, qi1.y, qi1.z};
    V3 pj  = {qj.x,  qj.y,  qj.z};
    V3 pj1 = {qj1.x, qj1.y, qj1.z};

    V3 u0 = v3sub(pj,  pi);
    V3 u1 = v3sub(pj1, pi);
    V3 u2 = v3sub(pj,  pi1);
    V3 u3 = v3sub(pj1, pi1);

    V3 c0 = v3cross(u0, u1);
    V3 c1 = v3cross(u1, u3);
    V3 c2 = v3cross(u3, u2);
    V3 c3 = v3cross(u2, u0);

    float r0 = __builtin_amdgcn_rsqf(v3dot(c0, c0));
    float r1 = __builtin_amdgcn_rsqf(v3dot(c1, c1));
    float r2 = __builtin_amdgcn_rsqf(v3dot(c2, c2));
    float r3 = __builtin_amdgcn_rsqf(v3dot(c3, c3));

    float omega = asin_fast(clamp1(v3dot(c0, c1) * (r0 * r1)))
                + asin_fast(clamp1(v3dot(c1, c2) * (r1 * r2)))
                + asin_fast(clamp1(v3dot(c2, c3) * (r2 * r3)))
                + asin_fast(clamp1(v3dot(c3, c0) * (r3 * r0)));

    float sg = v3dot(v3cross(v3sub(pj1, pj), v3sub(pi1, pi)), u0);
    float sign = (sg > 0.0f) ? 1.0f : ((sg < 0.0f) ? -1.0f : 0.0f);
    return omega * sign * ONE_OVER_2PI;
}

// edge -> (g, pp, k0) for node tau, edge index ee (branchless)
__device__ __forceinline__ void edge_compute(const float4* cs, int tau, int ee,
                                             float& g, float& pp, int& k0) {
    const int eT1 = (tau <= N_ATOMS - 2) ? tau - 1 : 0;
    const int typ = (ee < eT1) ? 0 : 1;
    const int a = (typ == 0) ? ee : ee - eT1 + 1;

    const float4 qa = cs[a];
    const float4 qt = cs[tau];
    const float dx = qa.x - qt.x;
    const float dy = qa.y - qt.y;
    const float dz = qa.z - qt.z;
    g = __expf(-(dx*dx + dy*dy + dz*dz));

    const float w = writhe_ij(cs, a - typ, tau - typ);
    pp = (w + 1.0f) * INV_STEP;          // pp - k = (w - c_k)/STEP
    k0 = __float2int_rn(pp);
}

// One 256-thread block per NODE PAIR (t0, t1) = (p+2, 255-p), same batch.
// 2 edges/thread: edge1 = tid (node0 if tid<E0, else node1), edge2 = tid+256
// (ALWAYS node1, since E0 <= 253 < 256). Both computed unconditionally
// (branchless) -> 2 independent writhe chains interleaved for ILP. 8 blocks/CU
// (vs 4 with 512-thr blocks): barrier stalls backfilled by 7 other blocks.
__global__ __launch_bounds__(256) void fused_kernel(const float* __restrict__ coords,
                                                    const float* __restrict__ nf,
                                                    const float* __restrict__ basis,
                                                    float* __restrict__ out) {
    const int blk = blockIdx.x;
    const int b = blk & 7;
    const int p = blk >> 3;            // pair index 0..126
    const int t0 = p + 2;              // 2..128
    const int t1 = 255 - p;            // 255..129
    const int tid = threadIdx.x;

    const int E0  = 2 * t0 - 3;                         // edges of node t0 (<=253)
    const int E1n = (t1 == 255) ? 253 : 2 * t1 - 3;     // edges of node t1
    const int E = E0 + E1n;                             // 508 (254 when p==0)

    const int nu_out = tid >> 7;       // 0: node t0 row, 1: node t1 row
    const int f_out = tid & 127;
    const int row_out = nu_out ? t1 : t0;
    const float mynf = nf[((size_t)((b << 8) | row_out)) * N_FEAT + f_out];

    __shared__ float4 cs[N_ATOMS];           // 4 KB, padded xyz0
    __shared__ float h2[2 * NHIST * BINS];   // 9.6 KB (two 4-copy histograms)
    __shared__ float sden[2];
    __shared__ int skmin[2], skmax[2];

    {
        const int gbase = ((b << 8) + tid) * 3;
        cs[tid] = make_float4(coords[gbase], coords[gbase + 1], coords[gbase + 2], 0.0f);
    }
    if (tid < 2) { sden[tid] = 0.0f; skmin[tid] = BINS - 1; skmax[tid] = 0; }
    __syncthreads();

    // ---- two independent edge computations (branchless; ILP) ----
    const bool act1 = (tid < E);                  // p>=1: always true
    const int node1e = (tid < E0) ? 0 : 1;
    const int ee1 = (node1e == 1) ? min(tid - E0, E1n - 1) : tid;
    const int tau1 = node1e ? t1 : t0;

    const bool act2 = (tid + 256 < E);            // edge2 always node 1
    const int ee2 = act2 ? (tid + 256 - E0) : 0;

    float g1, pp1; int k01;
    float g2, pp2; int k02;
    edge_compute(cs, tau1, ee1, g1, pp1, k01);
    edge_compute(cs, t1,   ee2, g2, pp2, k02);

    // ---- per-node range + denominator reduction ----
    float d0 = (act1 && node1e == 0) ? g1 : 0.0f;
    float d1 = ((act1 && node1e == 1) ? g1 : 0.0f) + (act2 ? g2 : 0.0f);
    int kn0 = BINS - 1, kx0 = 0, kn1 = BINS - 1, kx1 = 0;
    if (act1) {
        const int kmn = max(0, k01 - WIN), kmx = min(BINS - 1, k01 + WIN);
        if (node1e == 0) { kn0 = kmn; kx0 = kmx; } else { kn1 = kmn; kx1 = kmx; }
    }
    if (act2) {
        kn1 = min(kn1, max(0, k02 - WIN));
        kx1 = max(kx1, min(BINS - 1, k02 + WIN));
    }

    #pragma unroll
    for (int off = 32; off > 0; off >>= 1) {
        d0 += __shfl_xor(d0, off, 64);
        d1 += __shfl_xor(d1, off, 64);
        kn0 = min(kn0, __shfl_xor(kn0, off, 64));
        kx0 = max(kx0, __shfl_xor(kx0, off, 64));
        kn1 = min(kn1, __shfl_xor(kn1, off, 64));
        kx1 = max(kx1, __shfl_xor(kx1, off, 64));
    }
    if ((tid & 63) == 0) {
        atomicAdd(&sden[0], d0);
        atomicAdd(&sden[1], d1);
        atomicMin(&skmin[0], kn0);
        atomicMax(&skmax[0], kx0);
        atomicMin(&skmin[1], kn1);
        atomicMax(&skmax[1], kx1);
    }
    __syncthreads();

    // ---- lazy zero: touched range of all copies, both nodes ----
    {
        const int nu = tid >> 7;                 // 128 threads per node
        const int l = tid & 127;
        const int kmin = skmin[nu], kmax = skmax[nu];
        const int base = nu * NHIST * BINS;
        for (int k = kmin + l; k <= kmax; k += 128) {
            #pragma unroll
            for (int c = 0; c < NHIST; ++c) h2[base + c * BINS + k] = 0.0f;
        }
    }
    __syncthreads();

    // ---- deposits (exp-recurrence, g folded into seed) ----
    const int copy = tid & (NHIST - 1);
    if (act1) {
        const int base = (node1e * NHIST + copy) * BINS;
        const int klo = k01 - WIN;
        float d = pp1 - (float)klo;
        float e = g1 * __expf(-d * d);
        float u = __expf(2.0f * d - 1.0f);
        #pragma unroll
        for (int m = 0; m < WINW; ++m) {
            const int k = klo + m;
            if (k >= 0 && k < BINS) atomicAdd(&h2[base + k], e);
            e *= u;
            u *= EXPM2;
        }
    }
    if (act2) {
        const int base = (NHIST + copy) * BINS;  // node 1
        const int klo = k02 - WIN;
        float d = pp2 - (float)klo;
        float e = g2 * __expf(-d * d);
        float u = __expf(2.0f * d - 1.0f);
        #pragma unroll
        for (int m = 0; m < WINW; ++m) {
            const int k = klo + m;
            if (k >= 0 && k < BINS) atomicAdd(&h2[base + k], e);
            e *= u;
            u *= EXPM2;
        }
    }
    __syncthreads();

    // ---- combine the 4 copies per node, touched range only ----
    {
        const int nu = tid >> 7;
        const int kmin = skmin[nu], kmax = skmax[nu];
        const int base = nu * NHIST * BINS;
        for (int k = kmin + (tid & 127); k <= kmax; k += 128) {
            h2[base + k] = h2[base + k] + h2[base + BINS + k]
                         + h2[base + 2 * BINS + k] + h2[base + 3 * BINS + k];
        }
    }
    __syncthreads();

    // ---- projection + direct write: thread owns (node, feature) ----
    {
        const int kmin = skmin[nu_out], kmax = skmax[nu_out];
        const int base = nu_out * NHIST * BINS;
        float acc0 = 0.0f, acc1 = 0.0f;          // 2-way unrolled for ILP
        int k = kmin;
        for (; k + 1 <= kmax; k += 2) {
            acc0 = fmaf(h2[base + k],     basis[k * N_FEAT + f_out],       acc0);
            acc1 = fmaf(h2[base + k + 1], basis[(k + 1) * N_FEAT + f_out], acc1);
        }
        if (k <= kmax) acc0 = fmaf(h2[base + k], basis[k * N_FEAT + f_out], acc0);
        out[((size_t)((b << 8) | row_out)) * N_FEAT + f_out]
            = mynf + (acc0 + acc1) * (INV_112 / sden[nu_out]);
    }
    if (p == 0) {
        // passthrough rows t = 0, 1 (no incoming edges), from the (2,255) block
        const size_t idx = ((size_t)((b << 8) | nu_out)) * N_FEAT + f_out;
        out[idx] = nf[idx];
    }
}

extern "C" void kernel_launch(void* const* d_in, const int* in_sizes, int n_in,
                              void* d_out, int out_size, void* d_ws, size_t ws_size,
                              hipStream_t stream) {
    const float* coords = (const float*)d_in[0];   // (B*N, 3) f32
    const float* nf     = (const float*)d_in[1];   // (B*N, 128) f32
    const float* basis  = (const float*)d_in[2];   // (300, 128) f32
    float* out = (float*)d_out;                    // (B*N, 128) f32

    fused_kernel<<<BATCH * 127, 256, 0, stream>>>(coords, nf, basis, out);
}